// Round 7
// baseline (746.249 us; speedup 1.0000x reference)
//
#include <hip/hip_runtime.h>
#include <math.h>

#define DEPTHL 4
#define HEADS 8
#define DH 64
#define DIM 512
#define BATCH 4
#define SEQ 512
#define ROWS (BATCH*SEQ)
#define SCALE 0.125f
#define LNEPS 1e-5f

typedef __attribute__((ext_vector_type(8))) short bfrag;   // 8 bf16 (4 VGPR)
typedef __attribute__((ext_vector_type(4))) float ffrag;   // 4 f32 acc
typedef __attribute__((ext_vector_type(2))) _Float16 h2;
typedef __attribute__((ext_vector_type(4))) unsigned short u16x4;
typedef __attribute__((ext_vector_type(8))) unsigned short u16x8;
#define MFMA(a,b,c) __builtin_amdgcn_mfma_f32_16x16x32_bf16(a, b, c, 0, 0, 0)

__device__ __forceinline__ unsigned short f2bf(float f) {
    unsigned int u = __float_as_uint(f);
    u += 0x7fffu + ((u >> 16) & 1u);          // round-to-nearest-even
    return (unsigned short)(u >> 16);
}
__device__ __forceinline__ float bf2f(unsigned short b) {
    return __uint_as_float(((unsigned int)b) << 16);
}

// ---------------- weight fp32 -> bf16 (ALL layers: 6 arrays of [4][512][512]) ----------------
__global__ __launch_bounds__(256) void convw(
    const float* __restrict__ s0, const float* __restrict__ s1,
    const float* __restrict__ s2, const float* __restrict__ s3,
    const float* __restrict__ s4, const float* __restrict__ s5,
    unsigned short* __restrict__ dst)
{
    size_t idx = ((size_t)blockIdx.x * 256 + threadIdx.x) * 4;
    int seg = (int)(idx >> 20);               // 4*DIM*DIM = 1048576 per array
    int off = (int)(idx & 1048575);
    const float* s = seg == 0 ? s0 : seg == 1 ? s1 : seg == 2 ? s2 :
                     seg == 3 ? s3 : seg == 4 ? s4 : s5;
    float4 v = *(const float4*)(s + off);
    unsigned long long p = (unsigned long long)f2bf(v.x)
        | ((unsigned long long)f2bf(v.y) << 16)
        | ((unsigned long long)f2bf(v.z) << 32)
        | ((unsigned long long)f2bf(v.w) << 48);
    *(unsigned long long*)(dst + idx) = p;
}

// ---------------- block reduction helper ----------------
__device__ __forceinline__ void blk_sum4(float& a, float& b, float& c, float& d) {
    __shared__ float s[16];
    #pragma unroll
    for (int o = 32; o; o >>= 1) {
        a += __shfl_xor(a, o); b += __shfl_xor(b, o);
        c += __shfl_xor(c, o); d += __shfl_xor(d, o);
    }
    int w = threadIdx.x >> 6;
    if ((threadIdx.x & 63) == 0) { s[w*4+0]=a; s[w*4+1]=b; s[w*4+2]=c; s[w*4+3]=d; }
    __syncthreads();
    a = s[0]+s[4]+s[8]+s[12];
    b = s[1]+s[5]+s[9]+s[13];
    c = s[2]+s[6]+s[10]+s[14];
    d = s[3]+s[7]+s[11]+s[15];
    __syncthreads();
}

// ---------------- complex LayerNorm (fp32 in, bf16 out) ----------------
__global__ __launch_bounds__(256) void ln_kernel(
    const float* __restrict__ xr, const float* __restrict__ xi,
    const float* __restrict__ gr, const float* __restrict__ br,
    const float* __restrict__ gi, const float* __restrict__ bi,
    unsigned short* __restrict__ outr, unsigned short* __restrict__ outi)
{
    int row = blockIdx.x, t = threadIdx.x;
    float2 vr = ((const float2*)(xr + (size_t)row*DIM))[t];
    float2 vi = ((const float2*)(xi + (size_t)row*DIM))[t];
    float sr = vr.x+vr.y, qr = vr.x*vr.x+vr.y*vr.y;
    float si = vi.x+vi.y, qi = vi.x*vi.x+vi.y*vi.y;
    blk_sum4(sr, qr, si, qi);
    float mr = sr*(1.f/DIM), mi_ = si*(1.f/DIM);
    float rr = 1.f/sqrtf(qr*(1.f/DIM)-mr*mr+LNEPS);
    float ri = 1.f/sqrtf(qi*(1.f/DIM)-mi_*mi_+LNEPS);
    float2 g2r = ((const float2*)gr)[t], b2r = ((const float2*)br)[t];
    float2 g2i = ((const float2*)gi)[t], b2i = ((const float2*)bi)[t];
    float o0 = (vr.x-mr)*rr*g2r.x + b2r.x;
    float o1 = (vr.y-mr)*rr*g2r.y + b2r.y;
    float o2 = (vi.x-mi_)*ri*g2i.x + b2i.x;
    float o3 = (vi.y-mi_)*ri*g2i.y + b2i.y;
    unsigned int pr = (unsigned int)f2bf(o0) | ((unsigned int)f2bf(o1) << 16);
    unsigned int pi = (unsigned int)f2bf(o2) | ((unsigned int)f2bf(o3) << 16);
    ((unsigned int*)(outr + (size_t)row*DIM))[t] = pr;
    ((unsigned int*)(outi + (size_t)row*DIM))[t] = pi;
}

// ---------------- bf16 MFMA complex GEMM: out[r,e] = sum_k A[r,k]*W[e,k] ----------------
// grid (64, 8), block 256 = 4 waves (2x2), block tile 32(M)x64(N), wave 16x32.
// k-step 32 register pipeline (r5 structure — best measured variant).
template<int MODE>
__global__ __launch_bounds__(256, 4) void cgemm_mfma(
    const unsigned short* __restrict__ Ar, const unsigned short* __restrict__ Ai,
    const unsigned short* __restrict__ Wr, const unsigned short* __restrict__ Wi,
    unsigned short* __restrict__ Obr, unsigned short* __restrict__ Obi,
    float* __restrict__ Ofr, float* __restrict__ Ofi,
    const float* __restrict__ biasR, const float* __restrict__ biasI,
    const float* __restrict__ stepp, const float* __restrict__ lamb, int layer)
{
    int tid = threadIdx.x;
    int lane = tid & 63;
    int w = tid >> 6, wr = w >> 1, wc = w & 1;
    int lrow = lane & 15, lg = lane >> 4;
    int bm = blockIdx.x, bn = blockIdx.y;

    const unsigned short* pAr = Ar + (size_t)(bm*32 + wr*16 + lrow)*DIM + lg*8;
    const unsigned short* pAi = Ai + (size_t)(bm*32 + wr*16 + lrow)*DIM + lg*8;
    const unsigned short* pBr[2]; const unsigned short* pBi[2];
    #pragma unroll
    for (int nt = 0; nt < 2; ++nt) {
        int brow = bn*64 + wc*32 + nt*16 + lrow;
        pBr[nt] = Wr + (size_t)brow*DIM + lg*8;
        pBi[nt] = Wi + (size_t)brow*DIM + lg*8;
    }
    ffrag acc1[2], acc2[2], acci[2];
    #pragma unroll
    for (int nt = 0; nt < 2; ++nt) {
        acc1[nt] = (ffrag){0.f,0.f,0.f,0.f};
        acc2[nt] = (ffrag){0.f,0.f,0.f,0.f};
        acci[nt] = (ffrag){0.f,0.f,0.f,0.f};
    }

    bfrag a_r = *(const bfrag*)(pAr);
    bfrag a_i = *(const bfrag*)(pAi);
    bfrag b_r0 = *(const bfrag*)(pBr[0]), b_r1 = *(const bfrag*)(pBr[1]);
    bfrag b_i0 = *(const bfrag*)(pBi[0]), b_i1 = *(const bfrag*)(pBi[1]);

    #pragma unroll 2
    for (int k0 = 0; k0 < DIM - 32; k0 += 32) {
        bfrag na_r = *(const bfrag*)(pAr + k0 + 32);
        bfrag na_i = *(const bfrag*)(pAi + k0 + 32);
        bfrag nb_r0 = *(const bfrag*)(pBr[0] + k0 + 32);
        bfrag nb_r1 = *(const bfrag*)(pBr[1] + k0 + 32);
        bfrag nb_i0 = *(const bfrag*)(pBi[0] + k0 + 32);
        bfrag nb_i1 = *(const bfrag*)(pBi[1] + k0 + 32);
        acc1[0] = MFMA(a_r, b_r0, acc1[0]);
        acc2[0] = MFMA(a_i, b_i0, acc2[0]);
        acci[0] = MFMA(a_r, b_i0, acci[0]);
        acci[0] = MFMA(a_i, b_r0, acci[0]);
        acc1[1] = MFMA(a_r, b_r1, acc1[1]);
        acc2[1] = MFMA(a_i, b_i1, acc2[1]);
        acci[1] = MFMA(a_r, b_i1, acci[1]);
        acci[1] = MFMA(a_i, b_r1, acci[1]);
        a_r = na_r; a_i = na_i;
        b_r0 = nb_r0; b_r1 = nb_r1; b_i0 = nb_i0; b_i1 = nb_i1;
    }
    acc1[0] = MFMA(a_r, b_r0, acc1[0]);
    acc2[0] = MFMA(a_i, b_i0, acc2[0]);
    acci[0] = MFMA(a_r, b_i0, acci[0]);
    acci[0] = MFMA(a_i, b_r0, acci[0]);
    acc1[1] = MFMA(a_r, b_r1, acc1[1]);
    acc2[1] = MFMA(a_i, b_i1, acc2[1]);
    acci[1] = MFMA(a_r, b_i1, acci[1]);
    acci[1] = MFMA(a_i, b_r1, acci[1]);

    float ss = 0.f, sl = 0.f;
    if (MODE == 2) { ss = log1pf(expf(stepp[layer])); sl = ss * log1pf(expf(lamb[layer])); }

    #pragma unroll
    for (int nt = 0; nt < 2; ++nt) {
        int E = bn*64 + wc*32 + nt*16 + lrow;
        #pragma unroll
        for (int r = 0; r < 4; ++r) {
            int R = bm*32 + wr*16 + lg*4 + r;
            float re = acc1[nt][r] - acc2[nt][r];
            float im = acci[nt][r];
            if (MODE == 0) {
                int b = R >> 9, n = R & (SEQ-1);
                int h = E >> 6, d = E & 63;
                size_t off = (((size_t)(b*HEADS + h)*SEQ + n) << 6) + d;
                Obr[off] = f2bf(re);
                Obi[off] = f2bf(im);
            } else if (MODE == 1) {
                size_t off = (size_t)R*DIM + E;
                Ofr[off] = re + biasR[E] + Ofr[off];
                Ofi[off] = im + biasI[E] + Ofi[off];
            } else {
                size_t off = (size_t)R*DIM + E;
                float xnr_ = bf2f(Ar[off]), xni_ = bf2f(Ai[off]);
                Ofr[off] = fmaxf(xnr_ + ss*re - sl, 0.f);
                Ofi[off] = fmaxf(xni_ + ss*im, 0.f);
            }
        }
    }
}

// ---------------- V^T transpose: whT[bh][d][m] = wh[bh][m][d] ----------------
__global__ __launch_bounds__(256) void vT_kernel(
    const unsigned short* __restrict__ whr, const unsigned short* __restrict__ whi,
    unsigned short* __restrict__ whTr, unsigned short* __restrict__ whTi)
{
    __shared__ unsigned short sR[64][68], sI[64][68];
    int tid = threadIdx.x, mt = blockIdx.x, bh = blockIdx.y;
    const unsigned short* bR = whr + ((size_t)bh << 15) + (size_t)(mt << 6) * 64;
    const unsigned short* bI = whi + ((size_t)bh << 15) + (size_t)(mt << 6) * 64;
    int ml = tid >> 4, d4 = (tid & 15) * 4;
    #pragma unroll
    for (int jj = 0; jj < 4; ++jj) {
        int r_ = ml + jj*16;
        *(u16x4*)&sR[r_][d4] = *(const u16x4*)(bR + r_*64 + d4);
        *(u16x4*)&sI[r_][d4] = *(const u16x4*)(bI + r_*64 + d4);
    }
    __syncthreads();
    int d = tid >> 2, mo = (tid & 3) * 16;
    u16x8 vr0, vr1, vi0, vi1;
    #pragma unroll
    for (int jj = 0; jj < 8; ++jj) {
        vr0[jj] = sR[mo + jj][d];      vr1[jj] = sR[mo + 8 + jj][d];
        vi0[jj] = sI[mo + jj][d];      vi1[jj] = sI[mo + 8 + jj][d];
    }
    size_t off = ((size_t)bh*64 + d)*512 + (mt << 6) + mo;
    *(u16x8*)(whTr + off) = vr0;  *(u16x8*)(whTr + off + 8) = vr1;
    *(u16x8*)(whTi + off) = vi0;  *(u16x8*)(whTi + off + 8) = vi1;
}

// ---------------- batched QK^T: Z[bh][q][m] = SCALE * Q[q]·conj(K[m]) (fp16 out) ----------------
// grid (16 qt, 8 mt, 32 bh), block 256 = 4 waves (2 q-halves x 2 m-halves).
__global__ __launch_bounds__(256) void qk_kernel(
    const unsigned short* __restrict__ whr, const unsigned short* __restrict__ whi,
    _Float16* __restrict__ Zr, _Float16* __restrict__ Zi)
{
    int tid = threadIdx.x, lane = tid & 63;
    int w = tid >> 6, wr = w >> 1, wc = w & 1;
    int lrow = lane & 15, lg = lane >> 4;
    int qt = blockIdx.x, mt = blockIdx.y, bh = blockIdx.z;
    const unsigned short* baseR = whr + ((size_t)bh << 15);
    const unsigned short* baseI = whi + ((size_t)bh << 15);
    int qrow = qt*32 + wr*16 + lrow;
    bfrag qr0 = *(const bfrag*)(baseR + (qrow << 6) + lg*8);
    bfrag qr1 = *(const bfrag*)(baseR + (qrow << 6) + 32 + lg*8);
    bfrag qi0 = *(const bfrag*)(baseI + (qrow << 6) + lg*8);
    bfrag qi1 = *(const bfrag*)(baseI + (qrow << 6) + 32 + lg*8);

    ffrag aRR[2], aII[2], aIR[2], aRI[2];
    #pragma unroll
    for (int nt = 0; nt < 2; ++nt) {
        aRR[nt] = (ffrag){0.f,0.f,0.f,0.f};
        aII[nt] = (ffrag){0.f,0.f,0.f,0.f};
        aIR[nt] = (ffrag){0.f,0.f,0.f,0.f};
        aRI[nt] = (ffrag){0.f,0.f,0.f,0.f};
    }
    #pragma unroll
    for (int nt = 0; nt < 2; ++nt) {
        int mrow = mt*64 + wc*32 + nt*16 + lrow;
        bfrag kr0 = *(const bfrag*)(baseR + (mrow << 6) + lg*8);
        bfrag kr1 = *(const bfrag*)(baseR + (mrow << 6) + 32 + lg*8);
        bfrag ki0 = *(const bfrag*)(baseI + (mrow << 6) + lg*8);
        bfrag ki1 = *(const bfrag*)(baseI + (mrow << 6) + 32 + lg*8);
        aRR[nt] = MFMA(qr0, kr0, aRR[nt]);  aRR[nt] = MFMA(qr1, kr1, aRR[nt]);
        aII[nt] = MFMA(qi0, ki0, aII[nt]);  aII[nt] = MFMA(qi1, ki1, aII[nt]);
        aIR[nt] = MFMA(qi0, kr0, aIR[nt]);  aIR[nt] = MFMA(qi1, kr1, aIR[nt]);
        aRI[nt] = MFMA(qr0, ki0, aRI[nt]);  aRI[nt] = MFMA(qr1, ki1, aRI[nt]);
    }
    #pragma unroll
    for (int nt = 0; nt < 2; ++nt) {
        int m = mt*64 + wc*32 + nt*16 + lrow;
        #pragma unroll
        for (int r = 0; r < 4; ++r) {
            int q = qt*32 + wr*16 + lg*4 + r;
            size_t off = ((size_t)bh << 18) + ((size_t)q << 9) + m;
            Zr[off] = (_Float16)((aRR[nt][r] + aII[nt][r]) * SCALE);
            Zi[off] = (_Float16)((aIR[nt][r] - aRI[nt][r]) * SCALE);
        }
    }
}

// ---------------- magnitude softmax, phase preserved; bf16 P written IN PLACE over Z ----------------
// One wave per row (512 m); grid 4096 x 256 thr.
__global__ __launch_bounds__(256) void sm_kernel(
    _Float16* __restrict__ Zr, _Float16* __restrict__ Zi)
{
    int tid = threadIdx.x, lane = tid & 63, w = tid >> 6;
    size_t row = (size_t)blockIdx.x * 4 + w;
    _Float16* pr = Zr + (row << 9);
    _Float16* pi = Zi + (row << 9);
    float zr[8], zi[8], av[8], ev[8];
    float mx = -1e30f;
    #pragma unroll
    for (int j = 0; j < 4; ++j) {
        int m = j*128 + lane*2;
        h2 vr = *(const h2*)(pr + m);
        h2 vi = *(const h2*)(pi + m);
        zr[2*j] = (float)vr[0]; zr[2*j+1] = (float)vr[1];
        zi[2*j] = (float)vi[0]; zi[2*j+1] = (float)vi[1];
    }
    #pragma unroll
    for (int j = 0; j < 8; ++j) {
        av[j] = sqrtf(zr[j]*zr[j] + zi[j]*zi[j]);
        mx = fmaxf(mx, av[j]);
    }
    #pragma unroll
    for (int o = 32; o; o >>= 1) mx = fmaxf(mx, __shfl_xor(mx, o));
    float s = 0.f;
    #pragma unroll
    for (int j = 0; j < 8; ++j) { ev[j] = expf(av[j] - mx); s += ev[j]; }
    #pragma unroll
    for (int o = 32; o; o >>= 1) s += __shfl_xor(s, o);
    float inv = 1.f / s;
    #pragma unroll
    for (int j = 0; j < 4; ++j) {
        int m = j*128 + lane*2;
        float p0 = ev[2*j] * inv,  p1 = ev[2*j+1] * inv;
        float f0 = av[2*j]   > 0.f ? p0 / av[2*j]   : 0.f;
        float f1 = av[2*j+1] > 0.f ? p1 / av[2*j+1] : 0.f;
        float or0 = av[2*j]   > 0.f ? f0*zr[2*j]   : p0;
        float or1 = av[2*j+1] > 0.f ? f1*zr[2*j+1] : p1;
        float oi0 = f0*zi[2*j], oi1 = f1*zi[2*j+1];
        *(unsigned int*)(pr + m) = (unsigned int)f2bf(or0) | ((unsigned int)f2bf(or1) << 16);
        *(unsigned int*)(pi + m) = (unsigned int)f2bf(oi0) | ((unsigned int)f2bf(oi1) << 16);
    }
}

// ---------------- batched PV: out[q][d] = sum_m P[q,m]*V[m,d] ----------------
// grid (16 qt, 32 bh), block 256 = 4 waves (2 q x 2 d), wave 16q x 32d, K=512.
__global__ __launch_bounds__(256, 4) void pv_kernel(
    const unsigned short* __restrict__ Pr, const unsigned short* __restrict__ Pi,
    const unsigned short* __restrict__ whTr, const unsigned short* __restrict__ whTi,
    unsigned short* __restrict__ aor, unsigned short* __restrict__ aoi)
{
    int tid = threadIdx.x, lane = tid & 63;
    int w = tid >> 6, wr = w >> 1, wc = w & 1;
    int lrow = lane & 15, lg = lane >> 4;
    int qt = blockIdx.x, bh = blockIdx.y;

    const unsigned short* pA_r = Pr + ((size_t)bh << 18) + ((size_t)(qt*32 + wr*16 + lrow) << 9) + lg*8;
    const unsigned short* pA_i = Pi + ((size_t)bh << 18) + ((size_t)(qt*32 + wr*16 + lrow) << 9) + lg*8;
    const unsigned short* pB_r0 = whTr + ((size_t)bh*64 + wc*32 + lrow)*512 + lg*8;
    const unsigned short* pB_i0 = whTi + ((size_t)bh*64 + wc*32 + lrow)*512 + lg*8;
    const unsigned short* pB_r1 = pB_r0 + (size_t)16*512;
    const unsigned short* pB_i1 = pB_i0 + (size_t)16*512;

    ffrag c1[2], c2[2], ci[2];
    #pragma unroll
    for (int nt = 0; nt < 2; ++nt) {
        c1[nt] = (ffrag){0.f,0.f,0.f,0.f};
        c2[nt] = (ffrag){0.f,0.f,0.f,0.f};
        ci[nt] = (ffrag){0.f,0.f,0.f,0.f};
    }
    bfrag a_r = *(const bfrag*)(pA_r);
    bfrag a_i = *(const bfrag*)(pA_i);
    bfrag b_r0 = *(const bfrag*)(pB_r0), b_r1 = *(const bfrag*)(pB_r1);
    bfrag b_i0 = *(const bfrag*)(pB_i0), b_i1 = *(const bfrag*)(pB_i1);

    #pragma unroll 2
    for (int k0 = 0; k0 < 512 - 32; k0 += 32) {
        bfrag na_r  = *(const bfrag*)(pA_r  + k0 + 32);
        bfrag na_i  = *(const bfrag*)(pA_i  + k0 + 32);
        bfrag nb_r0 = *(const bfrag*)(pB_r0 + k0 + 32);
        bfrag nb_r1 = *(const bfrag*)(pB_r1 + k0 + 32);
        bfrag nb_i0 = *(const bfrag*)(pB_i0 + k0 + 32);
        bfrag nb_i1 = *(const bfrag*)(pB_i1 + k0 + 32);
        c1[0] = MFMA(a_r, b_r0, c1[0]);
        c2[0] = MFMA(a_i, b_i0, c2[0]);
        ci[0] = MFMA(a_r, b_i0, ci[0]);
        ci[0] = MFMA(a_i, b_r0, ci[0]);
        c1[1] = MFMA(a_r, b_r1, c1[1]);
        c2[1] = MFMA(a_i, b_i1, c2[1]);
        ci[1] = MFMA(a_r, b_i1, ci[1]);
        ci[1] = MFMA(a_i, b_r1, ci[1]);
        a_r = na_r; a_i = na_i;
        b_r0 = nb_r0; b_r1 = nb_r1; b_i0 = nb_i0; b_i1 = nb_i1;
    }
    c1[0] = MFMA(a_r, b_r0, c1[0]);
    c2[0] = MFMA(a_i, b_i0, c2[0]);
    ci[0] = MFMA(a_r, b_i0, ci[0]);
    ci[0] = MFMA(a_i, b_r0, ci[0]);
    c1[1] = MFMA(a_r, b_r1, c1[1]);
    c2[1] = MFMA(a_i, b_i1, c2[1]);
    ci[1] = MFMA(a_r, b_i1, ci[1]);
    ci[1] = MFMA(a_i, b_r1, ci[1]);

    int b = bh >> 3, h = bh & 7;
    #pragma unroll
    for (int nt = 0; nt < 2; ++nt) {
        int d = wc*32 + nt*16 + lrow;
        #pragma unroll
        for (int r = 0; r < 4; ++r) {
            int q = qt*32 + wr*16 + lg*4 + r;
            size_t off = (((size_t)(b*SEQ + q)) << 9) + h*64 + d;
            aor[off] = f2bf(c1[nt][r] - c2[nt][r]);
            aoi[off] = f2bf(ci[nt][r]);
        }
    }
}

// ---------------- launch ----------------
extern "C" void kernel_launch(void* const* d_in, const int* in_sizes, int n_in,
                              void* d_out, int out_size, void* d_ws, size_t ws_size,
                              hipStream_t stream)
{
    const float* x_real  = (const float*)d_in[0];
    const float* x_imag  = (const float*)d_in[1];
    const float* ln1_g_r = (const float*)d_in[2];
    const float* ln1_b_r = (const float*)d_in[3];
    const float* ln1_g_i = (const float*)d_in[4];
    const float* ln1_b_i = (const float*)d_in[5];
    const float* ln2_g_r = (const float*)d_in[6];
    const float* ln2_b_r = (const float*)d_in[7];
    const float* ln2_g_i = (const float*)d_in[8];
    const float* ln2_b_i = (const float*)d_in[9];
    const float* qkv_w_r = (const float*)d_in[10];
    const float* qkv_w_i = (const float*)d_in[11];
    const float* out_w_r = (const float*)d_in[12];
    const float* out_w_i = (const float*)d_in[13];
    const float* out_b_r = (const float*)d_in[14];
    const float* out_b_i = (const float*)d_in[15];
    const float* ff_w_r  = (const float*)d_in[16];
    const float* ff_w_i  = (const float*)d_in[17];
    const float* stepp   = (const float*)d_in[18];
    const float* lamb    = (const float*)d_in[19];

    const size_t SZ = (size_t)ROWS * DIM;       // 1M elems
    const size_t WSEG = (size_t)DIM * DIM;      // 256K elems
    const size_t WALL = 4 * WSEG;               // one weight array, all layers
    float* xr = (float*)d_ws;
    float* xi = xr + SZ;
    unsigned short* xnr  = (unsigned short*)(xi + SZ);
    unsigned short* xni  = xnr + SZ;
    unsigned short* whr  = xni + SZ;
    unsigned short* whi  = whr + SZ;
    unsigned short* aor  = whi + SZ;
    unsigned short* aoi  = aor + SZ;
    unsigned short* whTr = aoi + SZ;
    unsigned short* whTi = whTr + SZ;
    unsigned short* wb   = whTi + SZ;           // 6 arrays x [4][512][512] bf16 = 12 MB
    _Float16* Zr = (_Float16*)(wb + 6*WALL);    // [32][512][512] fp16 = 16.8 MB
    _Float16* Zi = Zr + ((size_t)32 << 18);

    float* outR = (float*)d_out;
    float* outI = outR + SZ;

    hipMemcpyAsync(xr, x_real, SZ*sizeof(float), hipMemcpyDeviceToDevice, stream);
    hipMemcpyAsync(xi, x_imag, SZ*sizeof(float), hipMemcpyDeviceToDevice, stream);

    convw<<<6144, 256, 0, stream>>>(qkv_w_r, qkv_w_i, out_w_r, out_w_i, ff_w_r, ff_w_i, wb);

    for (int l = 0; l < DEPTHL; ++l) {
        const size_t WO = (size_t)l * WSEG;
        const unsigned short* Wq_r = wb + 0*WALL + WO;
        const unsigned short* Wq_i = wb + 1*WALL + WO;
        const unsigned short* Wo_r = wb + 2*WALL + WO;
        const unsigned short* Wo_i = wb + 3*WALL + WO;
        const unsigned short* Wf_r = wb + 4*WALL + WO;
        const unsigned short* Wf_i = wb + 5*WALL + WO;

        ln_kernel<<<ROWS, 256, 0, stream>>>(xr, xi,
            ln1_g_r + l*DIM, ln1_b_r + l*DIM, ln1_g_i + l*DIM, ln1_b_i + l*DIM, xnr, xni);
        cgemm_mfma<0><<<dim3(64, 8), 256, 0, stream>>>(xnr, xni, Wq_r, Wq_i,
            whr, whi, nullptr, nullptr, nullptr, nullptr, nullptr, nullptr, l);
        vT_kernel<<<dim3(8, 32), 256, 0, stream>>>(whr, whi, whTr, whTi);
        qk_kernel<<<dim3(16, 8, 32), 256, 0, stream>>>(whr, whi, Zr, Zi);
        sm_kernel<<<4096, 256, 0, stream>>>(Zr, Zi);
        pv_kernel<<<dim3(16, 32), 256, 0, stream>>>(
            (const unsigned short*)Zr, (const unsigned short*)Zi, whTr, whTi, aor, aoi);
        cgemm_mfma<1><<<dim3(64, 8), 256, 0, stream>>>(aor, aoi, Wo_r, Wo_i,
            nullptr, nullptr, xr, xi, out_b_r + l*DIM, out_b_i + l*DIM, nullptr, nullptr, l);
        ln_kernel<<<ROWS, 256, 0, stream>>>(xr, xi,
            ln2_g_r + l*DIM, ln2_b_r + l*DIM, ln2_g_i + l*DIM, ln2_b_i + l*DIM, xnr, xni);
        float* dstR = (l == DEPTHL-1) ? outR : xr;
        float* dstI = (l == DEPTHL-1) ? outI : xi;
        cgemm_mfma<2><<<dim3(64, 8), 256, 0, stream>>>(xnr, xni, Wf_r, Wf_i,
            nullptr, nullptr, dstR, dstI, nullptr, nullptr, stepp, lamb, l);
    }
}

// Round 8
// 689.925 us; speedup vs baseline: 1.0816x; 1.0816x over previous
//
#include <hip/hip_runtime.h>
#include <math.h>

#define DEPTHL 4
#define HEADS 8
#define DH 64
#define DIM 512
#define BATCH 4
#define SEQ 512
#define ROWS (BATCH*SEQ)
#define SCALE 0.125f
#define LNEPS 1e-5f

typedef __attribute__((ext_vector_type(8))) short bfrag;   // 8 bf16 (4 VGPR)
typedef __attribute__((ext_vector_type(4))) float ffrag;   // 4 f32 acc
typedef __attribute__((ext_vector_type(4))) unsigned short u16x4;
typedef __attribute__((ext_vector_type(8))) unsigned short u16x8;
#define MFMA(a,b,c) __builtin_amdgcn_mfma_f32_16x16x32_bf16(a, b, c, 0, 0, 0)

__device__ __forceinline__ unsigned short f2bf(float f) {
    unsigned int u = __float_as_uint(f);
    u += 0x7fffu + ((u >> 16) & 1u);          // round-to-nearest-even
    return (unsigned short)(u >> 16);
}
__device__ __forceinline__ float bf2f(unsigned short b) {
    return __uint_as_float(((unsigned int)b) << 16);
}

// ---------------- weight fp32 -> bf16 (ALL layers: 6 arrays of [4][512][512]) ----------------
__global__ __launch_bounds__(256) void convw(
    const float* __restrict__ s0, const float* __restrict__ s1,
    const float* __restrict__ s2, const float* __restrict__ s3,
    const float* __restrict__ s4, const float* __restrict__ s5,
    unsigned short* __restrict__ dst)
{
    size_t idx = ((size_t)blockIdx.x * 256 + threadIdx.x) * 4;
    int seg = (int)(idx >> 20);               // 4*DIM*DIM = 1048576 per array
    int off = (int)(idx & 1048575);
    const float* s = seg == 0 ? s0 : seg == 1 ? s1 : seg == 2 ? s2 :
                     seg == 3 ? s3 : seg == 4 ? s4 : s5;
    float4 v = *(const float4*)(s + off);
    unsigned long long p = (unsigned long long)f2bf(v.x)
        | ((unsigned long long)f2bf(v.y) << 16)
        | ((unsigned long long)f2bf(v.z) << 32)
        | ((unsigned long long)f2bf(v.w) << 48);
    *(unsigned long long*)(dst + idx) = p;
}

// ---------------- block reduction helper ----------------
__device__ __forceinline__ void blk_sum4(float& a, float& b, float& c, float& d) {
    __shared__ float s[16];
    #pragma unroll
    for (int o = 32; o; o >>= 1) {
        a += __shfl_xor(a, o); b += __shfl_xor(b, o);
        c += __shfl_xor(c, o); d += __shfl_xor(d, o);
    }
    int w = threadIdx.x >> 6;
    if ((threadIdx.x & 63) == 0) { s[w*4+0]=a; s[w*4+1]=b; s[w*4+2]=c; s[w*4+3]=d; }
    __syncthreads();
    a = s[0]+s[4]+s[8]+s[12];
    b = s[1]+s[5]+s[9]+s[13];
    c = s[2]+s[6]+s[10]+s[14];
    d = s[3]+s[7]+s[11]+s[15];
    __syncthreads();
}

// ---------------- complex LayerNorm (fp32 in, bf16 out) ----------------
__global__ __launch_bounds__(256) void ln_kernel(
    const float* __restrict__ xr, const float* __restrict__ xi,
    const float* __restrict__ gr, const float* __restrict__ br,
    const float* __restrict__ gi, const float* __restrict__ bi,
    unsigned short* __restrict__ outr, unsigned short* __restrict__ outi)
{
    int row = blockIdx.x, t = threadIdx.x;
    float2 vr = ((const float2*)(xr + (size_t)row*DIM))[t];
    float2 vi = ((const float2*)(xi + (size_t)row*DIM))[t];
    float sr = vr.x+vr.y, qr = vr.x*vr.x+vr.y*vr.y;
    float si = vi.x+vi.y, qi = vi.x*vi.x+vi.y*vi.y;
    blk_sum4(sr, qr, si, qi);
    float mr = sr*(1.f/DIM), mi_ = si*(1.f/DIM);
    float rr = 1.f/sqrtf(qr*(1.f/DIM)-mr*mr+LNEPS);
    float ri = 1.f/sqrtf(qi*(1.f/DIM)-mi_*mi_+LNEPS);
    float2 g2r = ((const float2*)gr)[t], b2r = ((const float2*)br)[t];
    float2 g2i = ((const float2*)gi)[t], b2i = ((const float2*)bi)[t];
    float o0 = (vr.x-mr)*rr*g2r.x + b2r.x;
    float o1 = (vr.y-mr)*rr*g2r.y + b2r.y;
    float o2 = (vi.x-mi_)*ri*g2i.x + b2i.x;
    float o3 = (vi.y-mi_)*ri*g2i.y + b2i.y;
    unsigned int pr = (unsigned int)f2bf(o0) | ((unsigned int)f2bf(o1) << 16);
    unsigned int pi = (unsigned int)f2bf(o2) | ((unsigned int)f2bf(o3) << 16);
    ((unsigned int*)(outr + (size_t)row*DIM))[t] = pr;
    ((unsigned int*)(outi + (size_t)row*DIM))[t] = pi;
}

// ---------------- bf16 MFMA complex GEMM: out[r,e] = sum_k A[r,k]*W[e,k] ----------------
// grid (64, 8), block 512 = 8 waves (2 wr x 4 wc), block tile 32(M)x64(N), wave 16x16.
// 16 waves/CU (4/SIMD). k-step 32 register pipeline.
template<int MODE>
__global__ __launch_bounds__(512, 4) void cgemm_mfma(
    const unsigned short* __restrict__ Ar, const unsigned short* __restrict__ Ai,
    const unsigned short* __restrict__ Wr, const unsigned short* __restrict__ Wi,
    unsigned short* __restrict__ Obr, unsigned short* __restrict__ Obi,
    float* __restrict__ Ofr, float* __restrict__ Ofi,
    const float* __restrict__ biasR, const float* __restrict__ biasI,
    const float* __restrict__ stepp, const float* __restrict__ lamb, int layer)
{
    int tid = threadIdx.x;
    int lane = tid & 63;
    int w = tid >> 6, wr = w >> 2, wc = w & 3;
    int lrow = lane & 15, lg = lane >> 4;
    int bm = blockIdx.x, bn = blockIdx.y;

    const unsigned short* pAr = Ar + (size_t)(bm*32 + wr*16 + lrow)*DIM + lg*8;
    const unsigned short* pAi = Ai + (size_t)(bm*32 + wr*16 + lrow)*DIM + lg*8;
    const unsigned short* pBr = Wr + (size_t)(bn*64 + wc*16 + lrow)*DIM + lg*8;
    const unsigned short* pBi = Wi + (size_t)(bn*64 + wc*16 + lrow)*DIM + lg*8;

    ffrag acc1 = (ffrag){0.f,0.f,0.f,0.f};
    ffrag acc2 = (ffrag){0.f,0.f,0.f,0.f};
    ffrag acci = (ffrag){0.f,0.f,0.f,0.f};

    bfrag a_r = *(const bfrag*)(pAr);
    bfrag a_i = *(const bfrag*)(pAi);
    bfrag b_r = *(const bfrag*)(pBr);
    bfrag b_i = *(const bfrag*)(pBi);

    #pragma unroll 4
    for (int k0 = 0; k0 < DIM - 32; k0 += 32) {
        bfrag na_r = *(const bfrag*)(pAr + k0 + 32);
        bfrag na_i = *(const bfrag*)(pAi + k0 + 32);
        bfrag nb_r = *(const bfrag*)(pBr + k0 + 32);
        bfrag nb_i = *(const bfrag*)(pBi + k0 + 32);
        acc1 = MFMA(a_r, b_r, acc1);
        acc2 = MFMA(a_i, b_i, acc2);
        acci = MFMA(a_r, b_i, acci);
        acci = MFMA(a_i, b_r, acci);
        a_r = na_r; a_i = na_i; b_r = nb_r; b_i = nb_i;
    }
    acc1 = MFMA(a_r, b_r, acc1);
    acc2 = MFMA(a_i, b_i, acc2);
    acci = MFMA(a_r, b_i, acci);
    acci = MFMA(a_i, b_r, acci);

    float ss = 0.f, sl = 0.f;
    if (MODE == 2) { ss = log1pf(expf(stepp[layer])); sl = ss * log1pf(expf(lamb[layer])); }

    int E = bn*64 + wc*16 + lrow;
    #pragma unroll
    for (int r = 0; r < 4; ++r) {
        int R = bm*32 + wr*16 + lg*4 + r;
        float re = acc1[r] - acc2[r];
        float im = acci[r];
        if (MODE == 0) {
            int b = R >> 9, n = R & (SEQ-1);
            int h = E >> 6, d = E & 63;
            size_t off = (((size_t)(b*HEADS + h)*SEQ + n) << 6) + d;
            Obr[off] = f2bf(re);
            Obi[off] = f2bf(im);
        } else if (MODE == 1) {
            size_t off = (size_t)R*DIM + E;
            Ofr[off] = re + biasR[E] + Ofr[off];
            Ofi[off] = im + biasI[E] + Ofi[off];
        } else {
            size_t off = (size_t)R*DIM + E;
            float xnr_ = bf2f(Ar[off]), xni_ = bf2f(Ai[off]);
            Ofr[off] = fmaxf(xnr_ + ss*re - sl, 0.f);
            Ofi[off] = fmaxf(xni_ + ss*im, 0.f);
        }
    }
}

// ---------------- V^T transpose: whT[bh][d][m] = wh[bh][m][d] ----------------
__global__ __launch_bounds__(256) void vT_kernel(
    const unsigned short* __restrict__ whr, const unsigned short* __restrict__ whi,
    unsigned short* __restrict__ whTr, unsigned short* __restrict__ whTi)
{
    __shared__ unsigned short sR[64][68], sI[64][68];
    int tid = threadIdx.x, mt = blockIdx.x, bh = blockIdx.y;
    const unsigned short* bR = whr + ((size_t)bh << 15) + (size_t)(mt << 6) * 64;
    const unsigned short* bI = whi + ((size_t)bh << 15) + (size_t)(mt << 6) * 64;
    int ml = tid >> 4, d4 = (tid & 15) * 4;
    #pragma unroll
    for (int jj = 0; jj < 4; ++jj) {
        int r_ = ml + jj*16;
        *(u16x4*)&sR[r_][d4] = *(const u16x4*)(bR + r_*64 + d4);
        *(u16x4*)&sI[r_][d4] = *(const u16x4*)(bI + r_*64 + d4);
    }
    __syncthreads();
    int d = tid >> 2, mo = (tid & 3) * 16;
    u16x8 vr0, vr1, vi0, vi1;
    #pragma unroll
    for (int jj = 0; jj < 8; ++jj) {
        vr0[jj] = sR[mo + jj][d];      vr1[jj] = sR[mo + 8 + jj][d];
        vi0[jj] = sI[mo + jj][d];      vi1[jj] = sI[mo + 8 + jj][d];
    }
    size_t off = ((size_t)bh*64 + d)*512 + (mt << 6) + mo;
    *(u16x8*)(whTr + off) = vr0;  *(u16x8*)(whTr + off + 8) = vr1;
    *(u16x8*)(whTi + off) = vi0;  *(u16x8*)(whTi + off + 8) = vi1;
}

// ---------------- MFMA flash attention, barrier-free: 1 wave per block ----------------
// grid (32 bh, 32 qt of 16 q-rows). Wave scans all 512 m; V^T read from global
// (pre-transposed); P roundtrip through wave-private LDS (in-wave lgkmcnt only).
// z computed transposed (A=K, B=Q) so q = lane&15 -> per-lane flash state.
__global__ __launch_bounds__(64) void attn_mfma(
    const unsigned short* __restrict__ whr, const unsigned short* __restrict__ whi,
    const unsigned short* __restrict__ whTr, const unsigned short* __restrict__ whTi,
    unsigned short* __restrict__ aor, unsigned short* __restrict__ aoi)
{
    __shared__ __align__(16) unsigned short sP[2][16][40];
    __shared__ __align__(16) unsigned short sO[16][68];
    int lane = threadIdx.x;
    int lrow = lane & 15, lg = lane >> 4;
    int bh = blockIdx.x, qt = blockIdx.y;
    const unsigned short* baseR = whr + ((size_t)bh << 15);   // *512*64
    const unsigned short* baseI = whi + ((size_t)bh << 15);
    const unsigned short* vTr = whTr + ((size_t)bh << 15);    // [64 d][512 m]
    const unsigned short* vTi = whTi + ((size_t)bh << 15);
    int q0 = qt*16;

    bfrag qfr[2], qfi[2];
    #pragma unroll
    for (int ks = 0; ks < 2; ++ks) {
        qfr[ks] = *(const bfrag*)(baseR + ((size_t)(q0 + lrow) << 6) + ks*32 + lg*8);
        qfi[ks] = *(const bfrag*)(baseI + ((size_t)(q0 + lrow) << 6) + ks*32 + lg*8);
    }
    float M = -1e30f, S = 0.f;
    ffrag o1[4], o2[4], o3[4];   // O^T accs: SumVrPr, SumViPi, Sum(VrPi+ViPr)
    #pragma unroll
    for (int dt = 0; dt < 4; ++dt) {
        o1[dt] = (ffrag){0.f,0.f,0.f,0.f};
        o2[dt] = (ffrag){0.f,0.f,0.f,0.f};
        o3[dt] = (ffrag){0.f,0.f,0.f,0.f};
    }

    #pragma unroll 1
    for (int m0 = 0; m0 < SEQ; m0 += 32) {
        // V^T fragments for this m-tile (independent of softmax -> loads hide under QK)
        bfrag vfr[4], vfi[4];
        #pragma unroll
        for (int dt = 0; dt < 4; ++dt) {
            vfr[dt] = *(const bfrag*)(vTr + (size_t)(dt*16 + lrow)*512 + m0 + lg*8);
            vfi[dt] = *(const bfrag*)(vTi + (size_t)(dt*16 + lrow)*512 + m0 + lg*8);
        }
        // z^T[m][q] = sum_d K[m,d]*conj-combine Q[q,d]
        ffrag zr[2], zp[2], zm_[2];
        #pragma unroll
        for (int t = 0; t < 2; ++t) {
            zr[t] = (ffrag){0.f,0.f,0.f,0.f};
            zp[t] = (ffrag){0.f,0.f,0.f,0.f};
            zm_[t] = (ffrag){0.f,0.f,0.f,0.f};
        }
        #pragma unroll
        for (int t = 0; t < 2; ++t)
        #pragma unroll
        for (int ks = 0; ks < 2; ++ks) {
            bfrag kr = *(const bfrag*)(baseR + ((size_t)(m0 + t*16 + lrow) << 6) + ks*32 + lg*8);
            bfrag ki = *(const bfrag*)(baseI + ((size_t)(m0 + t*16 + lrow) << 6) + ks*32 + lg*8);
            zr[t]  = MFMA(kr, qfr[ks], zr[t]);
            zr[t]  = MFMA(ki, qfi[ks], zr[t]);
            zp[t]  = MFMA(kr, qfi[ks], zp[t]);
            zm_[t] = MFMA(ki, qfr[ks], zm_[t]);
        }
        // online softmax on |z|; lane's q = lrow; its 8 m: m0 + t*16 + lg*4 + r
        float av[2][4], rv[2][4], iv[2][4];
        float pmax = -1e30f;
        #pragma unroll
        for (int t = 0; t < 2; ++t)
        #pragma unroll
        for (int r = 0; r < 4; ++r) {
            float zrv = zr[t][r] * SCALE;
            float ziv = (zp[t][r] - zm_[t][r]) * SCALE;
            float a = sqrtf(zrv*zrv + ziv*ziv);
            av[t][r] = a; rv[t][r] = zrv; iv[t][r] = ziv;
            pmax = fmaxf(pmax, a);
        }
        pmax = fmaxf(pmax, __shfl_xor(pmax, 16));
        pmax = fmaxf(pmax, __shfl_xor(pmax, 32));
        float Mnew = fmaxf(M, pmax);
        float f = expf(M - Mnew);
        M = Mnew;
        S *= f;
        #pragma unroll
        for (int dt = 0; dt < 4; ++dt) { o1[dt] *= f; o2[dt] *= f; o3[dt] *= f; }
        float ssum = 0.f;
        #pragma unroll
        for (int t = 0; t < 2; ++t) {
            float ur[4], ui[4];
            #pragma unroll
            for (int r = 0; r < 4; ++r) {
                float a = av[t][r];
                float ee = expf(a - M);
                ssum += ee;
                float inva = a > 0.f ? ee / a : 0.f;
                ur[r] = a > 0.f ? inva * rv[t][r] : ee;
                ui[r] = inva * iv[t][r];
            }
            uint2 wpr, wpi;
            wpr.x = (unsigned int)f2bf(ur[0]) | ((unsigned int)f2bf(ur[1]) << 16);
            wpr.y = (unsigned int)f2bf(ur[2]) | ((unsigned int)f2bf(ur[3]) << 16);
            wpi.x = (unsigned int)f2bf(ui[0]) | ((unsigned int)f2bf(ui[1]) << 16);
            wpi.y = (unsigned int)f2bf(ui[2]) | ((unsigned int)f2bf(ui[3]) << 16);
            *(uint2*)&sP[0][lrow][t*16 + lg*4] = wpr;
            *(uint2*)&sP[1][lrow][t*16 + lg*4] = wpi;
        }
        ssum += __shfl_xor(ssum, 16);
        ssum += __shfl_xor(ssum, 32);
        S += ssum;
        // PV (in-wave LDS RAW handled by lgkmcnt; no barrier)
        bfrag pr = *(const bfrag*)&sP[0][lrow][lg*8];
        bfrag pi = *(const bfrag*)&sP[1][lrow][lg*8];
        #pragma unroll
        for (int dt = 0; dt < 4; ++dt) {
            o1[dt] = MFMA(vfr[dt], pr, o1[dt]);
            o2[dt] = MFMA(vfi[dt], pi, o2[dt]);
            o3[dt] = MFMA(vfr[dt], pi, o3[dt]);
            o3[dt] = MFMA(vfi[dt], pr, o3[dt]);
        }
    }

    // epilogue: O = O^T/S, restage via wave-private LDS for coalesced bf16 writes
    float invS = 1.f / S;
    int b = bh >> 3, h = bh & 7;
    #pragma unroll
    for (int dt = 0; dt < 4; ++dt) {
        uint2 p;
        p.x = (unsigned int)f2bf((o1[dt][0]-o2[dt][0])*invS)
            | ((unsigned int)f2bf((o1[dt][1]-o2[dt][1])*invS) << 16);
        p.y = (unsigned int)f2bf((o1[dt][2]-o2[dt][2])*invS)
            | ((unsigned int)f2bf((o1[dt][3]-o2[dt][3])*invS) << 16);
        *(uint2*)&sO[lrow][dt*16 + lg*4] = p;
    }
    {
        int q = lane >> 2, d0 = (lane & 3) * 16;
        u16x8 v0 = *(const u16x8*)&sO[q][d0];
        u16x8 v1 = *(const u16x8*)&sO[q][d0 + 8];
        size_t off = (((size_t)(b*SEQ + q0 + q)) << 9) + h*64 + d0;
        *(u16x8*)(aor + off) = v0;
        *(u16x8*)(aor + off + 8) = v1;
    }
    #pragma unroll
    for (int dt = 0; dt < 4; ++dt) {
        uint2 p;
        p.x = (unsigned int)f2bf(o3[dt][0]*invS) | ((unsigned int)f2bf(o3[dt][1]*invS) << 16);
        p.y = (unsigned int)f2bf(o3[dt][2]*invS) | ((unsigned int)f2bf(o3[dt][3]*invS) << 16);
        *(uint2*)&sO[lrow][dt*16 + lg*4] = p;
    }
    {
        int q = lane >> 2, d0 = (lane & 3) * 16;
        u16x8 v0 = *(const u16x8*)&sO[q][d0];
        u16x8 v1 = *(const u16x8*)&sO[q][d0 + 8];
        size_t off = (((size_t)(b*SEQ + q0 + q)) << 9) + h*64 + d0;
        *(u16x8*)(aoi + off) = v0;
        *(u16x8*)(aoi + off + 8) = v1;
    }
}

// ---------------- launch ----------------
extern "C" void kernel_launch(void* const* d_in, const int* in_sizes, int n_in,
                              void* d_out, int out_size, void* d_ws, size_t ws_size,
                              hipStream_t stream)
{
    const float* x_real  = (const float*)d_in[0];
    const float* x_imag  = (const float*)d_in[1];
    const float* ln1_g_r = (const float*)d_in[2];
    const float* ln1_b_r = (const float*)d_in[3];
    const float* ln1_g_i = (const float*)d_in[4];
    const float* ln1_b_i = (const float*)d_in[5];
    const float* ln2_g_r = (const float*)d_in[6];
    const float* ln2_b_r = (const float*)d_in[7];
    const float* ln2_g_i = (const float*)d_in[8];
    const float* ln2_b_i = (const float*)d_in[9];
    const float* qkv_w_r = (const float*)d_in[10];
    const float* qkv_w_i = (const float*)d_in[11];
    const float* out_w_r = (const float*)d_in[12];
    const float* out_w_i = (const float*)d_in[13];
    const float* out_b_r = (const float*)d_in[14];
    const float* out_b_i = (const float*)d_in[15];
    const float* ff_w_r  = (const float*)d_in[16];
    const float* ff_w_i  = (const float*)d_in[17];
    const float* stepp   = (const float*)d_in[18];
    const float* lamb    = (const float*)d_in[19];

    const size_t SZ = (size_t)ROWS * DIM;       // 1M elems
    const size_t WSEG = (size_t)DIM * DIM;      // 256K elems
    const size_t WALL = 4 * WSEG;               // one weight array, all layers
    float* xr = (float*)d_ws;
    float* xi = xr + SZ;
    unsigned short* xnr  = (unsigned short*)(xi + SZ);
    unsigned short* xni  = xnr + SZ;
    unsigned short* whr  = xni + SZ;
    unsigned short* whi  = whr + SZ;
    unsigned short* aor  = whi + SZ;
    unsigned short* aoi  = aor + SZ;
    unsigned short* whTr = aoi + SZ;
    unsigned short* whTi = whTr + SZ;
    unsigned short* wb   = whTi + SZ;           // 6 arrays x [4][512][512] bf16 = 12 MB

    float* outR = (float*)d_out;
    float* outI = outR + SZ;

    hipMemcpyAsync(xr, x_real, SZ*sizeof(float), hipMemcpyDeviceToDevice, stream);
    hipMemcpyAsync(xi, x_imag, SZ*sizeof(float), hipMemcpyDeviceToDevice, stream);

    convw<<<6144, 256, 0, stream>>>(qkv_w_r, qkv_w_i, out_w_r, out_w_i, ff_w_r, ff_w_i, wb);

    for (int l = 0; l < DEPTHL; ++l) {
        const size_t WO = (size_t)l * WSEG;
        const unsigned short* Wq_r = wb + 0*WALL + WO;
        const unsigned short* Wq_i = wb + 1*WALL + WO;
        const unsigned short* Wo_r = wb + 2*WALL + WO;
        const unsigned short* Wo_i = wb + 3*WALL + WO;
        const unsigned short* Wf_r = wb + 4*WALL + WO;
        const unsigned short* Wf_i = wb + 5*WALL + WO;

        ln_kernel<<<ROWS, 256, 0, stream>>>(xr, xi,
            ln1_g_r + l*DIM, ln1_b_r + l*DIM, ln1_g_i + l*DIM, ln1_b_i + l*DIM, xnr, xni);
        cgemm_mfma<0><<<dim3(64, 8), 512, 0, stream>>>(xnr, xni, Wq_r, Wq_i,
            whr, whi, nullptr, nullptr, nullptr, nullptr, nullptr, nullptr, l);
        vT_kernel<<<dim3(8, 32), 256, 0, stream>>>(whr, whi, whTr, whTi);
        attn_mfma<<<dim3(32, 32), 64, 0, stream>>>(whr, whi, whTr, whTi, aor, aoi);
        cgemm_mfma<1><<<dim3(64, 8), 512, 0, stream>>>(aor, aoi, Wo_r, Wo_i,
            nullptr, nullptr, xr, xi, out_b_r + l*DIM, out_b_i + l*DIM, nullptr, nullptr, l);
        ln_kernel<<<ROWS, 256, 0, stream>>>(xr, xi,
            ln2_g_r + l*DIM, ln2_b_r + l*DIM, ln2_g_i + l*DIM, ln2_b_i + l*DIM, xnr, xni);
        float* dstR = (l == DEPTHL-1) ? outR : xr;
        float* dstI = (l == DEPTHL-1) ? outI : xi;
        cgemm_mfma<2><<<dim3(64, 8), 512, 0, stream>>>(xnr, xni, Wf_r, Wf_i,
            nullptr, nullptr, dstR, dstI, nullptr, nullptr, stepp, lamb, l);
    }
}

// Round 9
// 617.513 us; speedup vs baseline: 1.2085x; 1.1173x over previous
//
#include <hip/hip_runtime.h>
#include <math.h>

#define DEPTHL 4
#define HEADS 8
#define DH 64
#define DIM 512
#define BATCH 4
#define SEQ 512
#define ROWS (BATCH*SEQ)
#define SCALE 0.125f
#define LNEPS 1e-5f

typedef __attribute__((ext_vector_type(8))) short bfrag;   // 8 bf16 (4 VGPR)
typedef __attribute__((ext_vector_type(4))) float ffrag;   // 4 f32 acc
typedef __attribute__((ext_vector_type(4))) unsigned short u16x4;
typedef __attribute__((ext_vector_type(8))) unsigned short u16x8;
#define MFMA(a,b,c) __builtin_amdgcn_mfma_f32_16x16x32_bf16(a, b, c, 0, 0, 0)

__device__ __forceinline__ unsigned short f2bf(float f) {
    unsigned int u = __float_as_uint(f);
    u += 0x7fffu + ((u >> 16) & 1u);          // round-to-nearest-even
    return (unsigned short)(u >> 16);
}
__device__ __forceinline__ float bf2f(unsigned short b) {
    return __uint_as_float(((unsigned int)b) << 16);
}

// ---------------- weight fp32 -> bf16 (ALL layers: 6 arrays of [4][512][512]) ----------------
__global__ __launch_bounds__(256) void convw(
    const float* __restrict__ s0, const float* __restrict__ s1,
    const float* __restrict__ s2, const float* __restrict__ s3,
    const float* __restrict__ s4, const float* __restrict__ s5,
    unsigned short* __restrict__ dst)
{
    size_t idx = ((size_t)blockIdx.x * 256 + threadIdx.x) * 4;
    int seg = (int)(idx >> 20);               // 4*DIM*DIM = 1048576 per array
    int off = (int)(idx & 1048575);
    const float* s = seg == 0 ? s0 : seg == 1 ? s1 : seg == 2 ? s2 :
                     seg == 3 ? s3 : seg == 4 ? s4 : s5;
    float4 v = *(const float4*)(s + off);
    unsigned long long p = (unsigned long long)f2bf(v.x)
        | ((unsigned long long)f2bf(v.y) << 16)
        | ((unsigned long long)f2bf(v.z) << 32)
        | ((unsigned long long)f2bf(v.w) << 48);
    *(unsigned long long*)(dst + idx) = p;
}

// ---------------- block reduction helper ----------------
__device__ __forceinline__ void blk_sum4(float& a, float& b, float& c, float& d) {
    __shared__ float s[16];
    #pragma unroll
    for (int o = 32; o; o >>= 1) {
        a += __shfl_xor(a, o); b += __shfl_xor(b, o);
        c += __shfl_xor(c, o); d += __shfl_xor(d, o);
    }
    int w = threadIdx.x >> 6;
    if ((threadIdx.x & 63) == 0) { s[w*4+0]=a; s[w*4+1]=b; s[w*4+2]=c; s[w*4+3]=d; }
    __syncthreads();
    a = s[0]+s[4]+s[8]+s[12];
    b = s[1]+s[5]+s[9]+s[13];
    c = s[2]+s[6]+s[10]+s[14];
    d = s[3]+s[7]+s[11]+s[15];
    __syncthreads();
}

// ---------------- complex LayerNorm (fp32 in, bf16 out) ----------------
__global__ __launch_bounds__(256) void ln_kernel(
    const float* __restrict__ xr, const float* __restrict__ xi,
    const float* __restrict__ gr, const float* __restrict__ br,
    const float* __restrict__ gi, const float* __restrict__ bi,
    unsigned short* __restrict__ outr, unsigned short* __restrict__ outi)
{
    int row = blockIdx.x, t = threadIdx.x;
    float2 vr = ((const float2*)(xr + (size_t)row*DIM))[t];
    float2 vi = ((const float2*)(xi + (size_t)row*DIM))[t];
    float sr = vr.x+vr.y, qr = vr.x*vr.x+vr.y*vr.y;
    float si = vi.x+vi.y, qi = vi.x*vi.x+vi.y*vi.y;
    blk_sum4(sr, qr, si, qi);
    float mr = sr*(1.f/DIM), mi_ = si*(1.f/DIM);
    float rr = 1.f/sqrtf(qr*(1.f/DIM)-mr*mr+LNEPS);
    float ri = 1.f/sqrtf(qi*(1.f/DIM)-mi_*mi_+LNEPS);
    float2 g2r = ((const float2*)gr)[t], b2r = ((const float2*)br)[t];
    float2 g2i = ((const float2*)gi)[t], b2i = ((const float2*)bi)[t];
    float o0 = (vr.x-mr)*rr*g2r.x + b2r.x;
    float o1 = (vr.y-mr)*rr*g2r.y + b2r.y;
    float o2 = (vi.x-mi_)*ri*g2i.x + b2i.x;
    float o3 = (vi.y-mi_)*ri*g2i.y + b2i.y;
    unsigned int pr = (unsigned int)f2bf(o0) | ((unsigned int)f2bf(o1) << 16);
    unsigned int pi = (unsigned int)f2bf(o2) | ((unsigned int)f2bf(o3) << 16);
    ((unsigned int*)(outr + (size_t)row*DIM))[t] = pr;
    ((unsigned int*)(outi + (size_t)row*DIM))[t] = pi;
}

// ---------------- bf16 MFMA complex GEMM: out[r,e] = sum_k A[r,k]*W[e,k] ----------------
// r5 structure (measured best): grid (64,8), block 256 = 4 waves (2x2),
// block tile 32(M)x64(N), wave 16x32, k-step 32 copy-chain prefetch, LB(256,4).
// MODE 0 additionally writes the transposed head layout whT[bh][d][m] (for PV).
template<int MODE>
__global__ __launch_bounds__(256, 4) void cgemm_mfma(
    const unsigned short* __restrict__ Ar, const unsigned short* __restrict__ Ai,
    const unsigned short* __restrict__ Wr, const unsigned short* __restrict__ Wi,
    unsigned short* __restrict__ Obr, unsigned short* __restrict__ Obi,
    unsigned short* __restrict__ OTr, unsigned short* __restrict__ OTi,
    float* __restrict__ Ofr, float* __restrict__ Ofi,
    const float* __restrict__ resR, const float* __restrict__ resI,
    const float* __restrict__ biasR, const float* __restrict__ biasI,
    const float* __restrict__ stepp, const float* __restrict__ lamb, int layer)
{
    int tid = threadIdx.x;
    int lane = tid & 63;
    int w = tid >> 6, wr = w >> 1, wc = w & 1;
    int lrow = lane & 15, lg = lane >> 4;
    int bm = blockIdx.x, bn = blockIdx.y;

    const unsigned short* pAr = Ar + (size_t)(bm*32 + wr*16 + lrow)*DIM + lg*8;
    const unsigned short* pAi = Ai + (size_t)(bm*32 + wr*16 + lrow)*DIM + lg*8;
    const unsigned short* pBr[2]; const unsigned short* pBi[2];
    #pragma unroll
    for (int nt = 0; nt < 2; ++nt) {
        int brow = bn*64 + wc*32 + nt*16 + lrow;
        pBr[nt] = Wr + (size_t)brow*DIM + lg*8;
        pBi[nt] = Wi + (size_t)brow*DIM + lg*8;
    }
    ffrag acc1[2], acc2[2], acci[2];
    #pragma unroll
    for (int nt = 0; nt < 2; ++nt) {
        acc1[nt] = (ffrag){0.f,0.f,0.f,0.f};
        acc2[nt] = (ffrag){0.f,0.f,0.f,0.f};
        acci[nt] = (ffrag){0.f,0.f,0.f,0.f};
    }

    bfrag a_r = *(const bfrag*)(pAr);
    bfrag a_i = *(const bfrag*)(pAi);
    bfrag b_r0 = *(const bfrag*)(pBr[0]), b_r1 = *(const bfrag*)(pBr[1]);
    bfrag b_i0 = *(const bfrag*)(pBi[0]), b_i1 = *(const bfrag*)(pBi[1]);

    #pragma unroll 2
    for (int k0 = 0; k0 < DIM - 32; k0 += 32) {
        bfrag na_r = *(const bfrag*)(pAr + k0 + 32);
        bfrag na_i = *(const bfrag*)(pAi + k0 + 32);
        bfrag nb_r0 = *(const bfrag*)(pBr[0] + k0 + 32);
        bfrag nb_r1 = *(const bfrag*)(pBr[1] + k0 + 32);
        bfrag nb_i0 = *(const bfrag*)(pBi[0] + k0 + 32);
        bfrag nb_i1 = *(const bfrag*)(pBi[1] + k0 + 32);
        acc1[0] = MFMA(a_r, b_r0, acc1[0]);
        acc2[0] = MFMA(a_i, b_i0, acc2[0]);
        acci[0] = MFMA(a_r, b_i0, acci[0]);
        acci[0] = MFMA(a_i, b_r0, acci[0]);
        acc1[1] = MFMA(a_r, b_r1, acc1[1]);
        acc2[1] = MFMA(a_i, b_i1, acc2[1]);
        acci[1] = MFMA(a_r, b_i1, acci[1]);
        acci[1] = MFMA(a_i, b_r1, acci[1]);
        a_r = na_r; a_i = na_i;
        b_r0 = nb_r0; b_r1 = nb_r1; b_i0 = nb_i0; b_i1 = nb_i1;
    }
    acc1[0] = MFMA(a_r, b_r0, acc1[0]);
    acc2[0] = MFMA(a_i, b_i0, acc2[0]);
    acci[0] = MFMA(a_r, b_i0, acci[0]);
    acci[0] = MFMA(a_i, b_r0, acci[0]);
    acc1[1] = MFMA(a_r, b_r1, acc1[1]);
    acc2[1] = MFMA(a_i, b_i1, acc2[1]);
    acci[1] = MFMA(a_r, b_i1, acci[1]);
    acci[1] = MFMA(a_i, b_r1, acci[1]);

    float ss = 0.f, sl = 0.f;
    if (MODE == 2) { ss = log1pf(expf(stepp[layer])); sl = ss * log1pf(expf(lamb[layer])); }

    if (MODE == 0) {
        int R0 = bm*32 + wr*16 + lg*4;
        int b = R0 >> 9, n0 = R0 & (SEQ-1);
        #pragma unroll
        for (int nt = 0; nt < 2; ++nt) {
            int E = bn*64 + wc*32 + nt*16 + lrow;
            int h = E >> 6, d = E & 63;
            u16x4 tr, ti;
            #pragma unroll
            for (int r = 0; r < 4; ++r) {
                unsigned short br_ = f2bf(acc1[nt][r] - acc2[nt][r]);
                unsigned short bi_ = f2bf(acci[nt][r]);
                size_t off = (((size_t)(b*HEADS + h)*SEQ + (n0 + r)) << 6) + d;
                Obr[off] = br_;  Obi[off] = bi_;
                tr[r] = br_;     ti[r] = bi_;
            }
            size_t offT = (((size_t)((b*HEADS + h)*64 + d)) << 9) + n0;
            *(u16x4*)(OTr + offT) = tr;
            *(u16x4*)(OTi + offT) = ti;
        }
    } else {
        #pragma unroll
        for (int nt = 0; nt < 2; ++nt) {
            int E = bn*64 + wc*32 + nt*16 + lrow;
            #pragma unroll
            for (int r = 0; r < 4; ++r) {
                int R = bm*32 + wr*16 + lg*4 + r;
                float re = acc1[nt][r] - acc2[nt][r];
                float im = acci[nt][r];
                size_t off = (size_t)R*DIM + E;
                if (MODE == 1) {
                    Ofr[off] = re + biasR[E] + resR[off];
                    Ofi[off] = im + biasI[E] + resI[off];
                } else {
                    float xnr_ = bf2f(Ar[off]), xni_ = bf2f(Ai[off]);
                    Ofr[off] = fmaxf(xnr_ + ss*re - sl, 0.f);
                    Ofi[off] = fmaxf(xni_ + ss*im, 0.f);
                }
            }
        }
    }
}

// ---------------- MFMA attention, NO-MAX softmax on |z| (phase preserved) ----------------
// Scores a = |z|*SCALE are bounded (<<88), so exp(a) cannot overflow fp32 and the
// online-max rescale chain is unnecessary: S and O accumulate associatively ->
// iterations software-pipeline freely. P roundtrips through DOUBLE-BUFFERED
// wave-private LDS (two distinct arrays -> no WAR serialization).
// grid (32 bh, 32 qt of 16 q-rows), 1 wave per block.
// z computed transposed (A=K, B=Q) so q = lane&15 -> per-lane state.
__global__ __launch_bounds__(64) void attn_mfma(
    const unsigned short* __restrict__ whr, const unsigned short* __restrict__ whi,
    const unsigned short* __restrict__ whTr, const unsigned short* __restrict__ whTi,
    unsigned short* __restrict__ aor, unsigned short* __restrict__ aoi)
{
    __shared__ __align__(16) unsigned short sPa[2][16][40];
    __shared__ __align__(16) unsigned short sPb[2][16][40];
    __shared__ __align__(16) unsigned short sO[16][68];
    int lane = threadIdx.x;
    int lrow = lane & 15, lg = lane >> 4;
    int bh = blockIdx.x, qt = blockIdx.y;
    const unsigned short* baseR = whr + ((size_t)bh << 15);   // *512*64
    const unsigned short* baseI = whi + ((size_t)bh << 15);
    const unsigned short* vTr = whTr + ((size_t)bh << 15);    // [64 d][512 m]
    const unsigned short* vTi = whTi + ((size_t)bh << 15);
    int q0 = qt*16;

    bfrag qfr[2], qfi[2];
    #pragma unroll
    for (int ks = 0; ks < 2; ++ks) {
        qfr[ks] = *(const bfrag*)(baseR + ((size_t)(q0 + lrow) << 6) + ks*32 + lg*8);
        qfi[ks] = *(const bfrag*)(baseI + ((size_t)(q0 + lrow) << 6) + ks*32 + lg*8);
    }
    float S = 0.f;
    ffrag o1[4], o2[4], o3[4];   // O^T accs: SumVrPr, SumViPi, Sum(VrPi+ViPr)
    #pragma unroll
    for (int dt = 0; dt < 4; ++dt) {
        o1[dt] = (ffrag){0.f,0.f,0.f,0.f};
        o2[dt] = (ffrag){0.f,0.f,0.f,0.f};
        o3[dt] = (ffrag){0.f,0.f,0.f,0.f};
    }

    auto iter = [&](int m0, unsigned short (&sP)[2][16][40]) {
        // V^T fragments (independent of softmax -> hide under QK)
        bfrag vfr[4], vfi[4];
        #pragma unroll
        for (int dt = 0; dt < 4; ++dt) {
            vfr[dt] = *(const bfrag*)(vTr + (size_t)(dt*16 + lrow)*512 + m0 + lg*8);
            vfi[dt] = *(const bfrag*)(vTi + (size_t)(dt*16 + lrow)*512 + m0 + lg*8);
        }
        // z^T[m][q] = sum_d K[m,d]*conj-combine Q[q,d]
        ffrag zr[2], zp[2], zm_[2];
        #pragma unroll
        for (int t = 0; t < 2; ++t) {
            zr[t] = (ffrag){0.f,0.f,0.f,0.f};
            zp[t] = (ffrag){0.f,0.f,0.f,0.f};
            zm_[t] = (ffrag){0.f,0.f,0.f,0.f};
        }
        #pragma unroll
        for (int t = 0; t < 2; ++t)
        #pragma unroll
        for (int ks = 0; ks < 2; ++ks) {
            bfrag kr = *(const bfrag*)(baseR + ((size_t)(m0 + t*16 + lrow) << 6) + ks*32 + lg*8);
            bfrag ki = *(const bfrag*)(baseI + ((size_t)(m0 + t*16 + lrow) << 6) + ks*32 + lg*8);
            zr[t]  = MFMA(kr, qfr[ks], zr[t]);
            zr[t]  = MFMA(ki, qfi[ks], zr[t]);
            zp[t]  = MFMA(kr, qfi[ks], zp[t]);
            zm_[t] = MFMA(ki, qfr[ks], zm_[t]);
        }
        // no-max softmax terms: e = exp(|z|*SCALE), P~ = e * z/|z|
        float ssum = 0.f;
        #pragma unroll
        for (int t = 0; t < 2; ++t) {
            float ur[4], ui[4];
            #pragma unroll
            for (int r = 0; r < 4; ++r) {
                float zrv = zr[t][r] * SCALE;
                float ziv = (zp[t][r] - zm_[t][r]) * SCALE;
                float mag2 = zrv*zrv + ziv*ziv;
                float g = mag2 > 0.f ? mag2 : 1.f;
                float rq = __frsqrt_rn(g);
                float amag = mag2 > 0.f ? mag2*rq : 0.f;   // |z|*SCALE
                float e = __expf(amag);
                ssum += e;
                float pf = e * rq;
                ur[r] = mag2 > 0.f ? pf*zrv : e;
                ui[r] = pf*ziv;
            }
            uint2 wpr, wpi;
            wpr.x = (unsigned int)f2bf(ur[0]) | ((unsigned int)f2bf(ur[1]) << 16);
            wpr.y = (unsigned int)f2bf(ur[2]) | ((unsigned int)f2bf(ur[3]) << 16);
            wpi.x = (unsigned int)f2bf(ui[0]) | ((unsigned int)f2bf(ui[1]) << 16);
            wpi.y = (unsigned int)f2bf(ui[2]) | ((unsigned int)f2bf(ui[3]) << 16);
            *(uint2*)&sP[0][lrow][t*16 + lg*4] = wpr;
            *(uint2*)&sP[1][lrow][t*16 + lg*4] = wpi;
        }
        ssum += __shfl_xor(ssum, 16);
        ssum += __shfl_xor(ssum, 32);
        S += ssum;
        // PV (in-wave LDS RAW via lgkmcnt; no barrier, no rescale)
        bfrag pr = *(const bfrag*)&sP[0][lrow][lg*8];
        bfrag pi = *(const bfrag*)&sP[1][lrow][lg*8];
        #pragma unroll
        for (int dt = 0; dt < 4; ++dt) {
            o1[dt] = MFMA(vfr[dt], pr, o1[dt]);
            o2[dt] = MFMA(vfi[dt], pi, o2[dt]);
            o3[dt] = MFMA(vfr[dt], pi, o3[dt]);
            o3[dt] = MFMA(vfi[dt], pr, o3[dt]);
        }
    };

    #pragma unroll 1
    for (int mo = 0; mo < SEQ; mo += 64) {
        iter(mo, sPa);
        iter(mo + 32, sPb);
    }

    // epilogue: O = O^T/S, restage via wave-private LDS for coalesced bf16 writes
    float invS = 1.f / S;
    int b = bh >> 3, h = bh & 7;
    #pragma unroll
    for (int dt = 0; dt < 4; ++dt) {
        uint2 p;
        p.x = (unsigned int)f2bf((o1[dt][0]-o2[dt][0])*invS)
            | ((unsigned int)f2bf((o1[dt][1]-o2[dt][1])*invS) << 16);
        p.y = (unsigned int)f2bf((o1[dt][2]-o2[dt][2])*invS)
            | ((unsigned int)f2bf((o1[dt][3]-o2[dt][3])*invS) << 16);
        *(uint2*)&sO[lrow][dt*16 + lg*4] = p;
    }
    {
        int q = lane >> 2, d0 = (lane & 3) * 16;
        u16x8 v0 = *(const u16x8*)&sO[q][d0];
        u16x8 v1 = *(const u16x8*)&sO[q][d0 + 8];
        size_t off = (((size_t)(b*SEQ + q0 + q)) << 9) + h*64 + d0;
        *(u16x8*)(aor + off) = v0;
        *(u16x8*)(aor + off + 8) = v1;
    }
    #pragma unroll
    for (int dt = 0; dt < 4; ++dt) {
        uint2 p;
        p.x = (unsigned int)f2bf(o3[dt][0]*invS) | ((unsigned int)f2bf(o3[dt][1]*invS) << 16);
        p.y = (unsigned int)f2bf(o3[dt][2]*invS) | ((unsigned int)f2bf(o3[dt][3]*invS) << 16);
        *(uint2*)&sO[lrow][dt*16 + lg*4] = p;
    }
    {
        int q = lane >> 2, d0 = (lane & 3) * 16;
        u16x8 v0 = *(const u16x8*)&sO[q][d0];
        u16x8 v1 = *(const u16x8*)&sO[q][d0 + 8];
        size_t off = (((size_t)(b*SEQ + q0 + q)) << 9) + h*64 + d0;
        *(u16x8*)(aoi + off) = v0;
        *(u16x8*)(aoi + off + 8) = v1;
    }
}

// ---------------- launch ----------------
extern "C" void kernel_launch(void* const* d_in, const int* in_sizes, int n_in,
                              void* d_out, int out_size, void* d_ws, size_t ws_size,
                              hipStream_t stream)
{
    const float* x_real  = (const float*)d_in[0];
    const float* x_imag  = (const float*)d_in[1];
    const float* ln1_g_r = (const float*)d_in[2];
    const float* ln1_b_r = (const float*)d_in[3];
    const float* ln1_g_i = (const float*)d_in[4];
    const float* ln1_b_i = (const float*)d_in[5];
    const float* ln2_g_r = (const float*)d_in[6];
    const float* ln2_b_r = (const float*)d_in[7];
    const float* ln2_g_i = (const float*)d_in[8];
    const float* ln2_b_i = (const float*)d_in[9];
    const float* qkv_w_r = (const float*)d_in[10];
    const float* qkv_w_i = (const float*)d_in[11];
    const float* out_w_r = (const float*)d_in[12];
    const float* out_w_i = (const float*)d_in[13];
    const float* out_b_r = (const float*)d_in[14];
    const float* out_b_i = (const float*)d_in[15];
    const float* ff_w_r  = (const float*)d_in[16];
    const float* ff_w_i  = (const float*)d_in[17];
    const float* stepp   = (const float*)d_in[18];
    const float* lamb    = (const float*)d_in[19];

    const size_t SZ = (size_t)ROWS * DIM;       // 1M elems
    const size_t WSEG = (size_t)DIM * DIM;      // 256K elems
    const size_t WALL = 4 * WSEG;               // one weight array, all layers
    float* xr = (float*)d_ws;
    float* xi = xr + SZ;
    unsigned short* xnr  = (unsigned short*)(xi + SZ);
    unsigned short* xni  = xnr + SZ;
    unsigned short* whr  = xni + SZ;
    unsigned short* whi  = whr + SZ;
    unsigned short* aor  = whi + SZ;
    unsigned short* aoi  = aor + SZ;
    unsigned short* whTr = aoi + SZ;
    unsigned short* whTi = whTr + SZ;
    unsigned short* wb   = whTi + SZ;           // 6 arrays x [4][512][512] bf16 = 12 MB

    float* outR = (float*)d_out;
    float* outI = outR + SZ;

    convw<<<6144, 256, 0, stream>>>(qkv_w_r, qkv_w_i, out_w_r, out_w_i, ff_w_r, ff_w_i, wb);

    for (int l = 0; l < DEPTHL; ++l) {
        const size_t WO = (size_t)l * WSEG;
        const unsigned short* Wq_r = wb + 0*WALL + WO;
        const unsigned short* Wq_i = wb + 1*WALL + WO;
        const unsigned short* Wo_r = wb + 2*WALL + WO;
        const unsigned short* Wo_i = wb + 3*WALL + WO;
        const unsigned short* Wf_r = wb + 4*WALL + WO;
        const unsigned short* Wf_i = wb + 5*WALL + WO;
        const float* curR = (l == 0) ? x_real : xr;
        const float* curI = (l == 0) ? x_imag : xi;

        ln_kernel<<<ROWS, 256, 0, stream>>>(curR, curI,
            ln1_g_r + l*DIM, ln1_b_r + l*DIM, ln1_g_i + l*DIM, ln1_b_i + l*DIM, xnr, xni);
        cgemm_mfma<0><<<dim3(64, 8), 256, 0, stream>>>(xnr, xni, Wq_r, Wq_i,
            whr, whi, whTr, whTi, nullptr, nullptr, nullptr, nullptr,
            nullptr, nullptr, nullptr, nullptr, l);
        attn_mfma<<<dim3(32, 32), 64, 0, stream>>>(whr, whi, whTr, whTi, aor, aoi);
        cgemm_mfma<1><<<dim3(64, 8), 256, 0, stream>>>(aor, aoi, Wo_r, Wo_i,
            nullptr, nullptr, nullptr, nullptr, xr, xi, curR, curI,
            out_b_r + l*DIM, out_b_i + l*DIM, nullptr, nullptr, l);
        ln_kernel<<<ROWS, 256, 0, stream>>>(xr, xi,
            ln2_g_r + l*DIM, ln2_b_r + l*DIM, ln2_g_i + l*DIM, ln2_b_i + l*DIM, xnr, xni);
        float* dstR = (l == DEPTHL-1) ? outR : xr;
        float* dstI = (l == DEPTHL-1) ? outI : xi;
        cgemm_mfma<2><<<dim3(64, 8), 256, 0, stream>>>(xnr, xni, Wf_r, Wf_i,
            nullptr, nullptr, nullptr, nullptr, dstR, dstI, nullptr, nullptr,
            nullptr, nullptr, stepp, lamb, l);
    }
}